// Round 5
// baseline (552.731 us; speedup 1.0000x reference)
//
#include <hip/hip_runtime.h>
#include <hip/hip_bf16.h>
#include <cstddef>

#define N_NODES 100000
#define N_EDGES 1600000
#define IN_C 512
#define HID_C 128
#define OUT_C 40
#define EPB 8000    // edges per partition block
#define NPART 200   // ceil(N_EDGES / EPB)
#define NBKT 196    // buckets of 512 nodes (dst >> 9); 99999>>9 = 195
#define BSHIFT 9

typedef short bf16x8 __attribute__((ext_vector_type(8)));
typedef float f32x4 __attribute__((ext_vector_type(4)));

__device__ __forceinline__ float bf2f(unsigned short u) {
    union { unsigned int i; float f; } v; v.i = ((unsigned int)u) << 16; return v.f;
}
__device__ __forceinline__ float bf2f_lo(unsigned int u) {
    union { unsigned int i; float f; } v; v.i = u << 16; return v.f;
}
__device__ __forceinline__ float bf2f_hi(unsigned int u) {
    union { unsigned int i; float f; } v; v.i = u & 0xFFFF0000u; return v.f;
}
__device__ __forceinline__ unsigned short f2bf(float f) {
    union { float f; unsigned int i; } v; v.f = f;
    unsigned int x = v.i;
    return (unsigned short)((x + 0x7FFFu + ((x >> 16) & 1u)) >> 16);  // RNE
}

// async 16B global -> LDS (wave-uniform LDS base + lane*16 dest; per-lane global src)
__device__ __forceinline__ void glds16(const void* g, void* l) {
    __builtin_amdgcn_global_load_lds(
        (const __attribute__((address_space(1))) unsigned int*)g,
        (__attribute__((address_space(3))) unsigned int*)l,
        16, 0, 0);
}

// ---- dtype detection -------------------------------------------------------
__global__ void k_detect(const unsigned int* __restrict__ xbits,
                         const int* __restrict__ ei32, int* __restrict__ flags) {
    if (threadIdx.x == 0 && blockIdx.x == 0) {
        int inrange = 0;
        for (int i = 0; i < 64; i++) {
            unsigned int b = xbits[i * 33 + 1];
            int e = (int)((b >> 23) & 0xFFu);
            if (e >= 90 && e <= 160) inrange++;
        }
        flags[0] = (inrange >= 32) ? 0 : 1;
        int zeros = 0;
        for (int i = 0; i < 8; i++) if (ei32[2 * i + 1] == 0) zeros++;
        flags[1] = (zeros == 8) ? 1 : 0;
    }
}

__device__ __forceinline__ int load_src(const int* ei, int mi, int e) {
    return mi ? ei[2 * e] : ei[e];
}
__device__ __forceinline__ int load_dst(const int* ei, int mi, int e) {
    return mi ? ei[2 * (N_EDGES + e)] : ei[N_EDGES + e];
}

// ---- weight/bias normalization ---------------------------------------------
#define NW_TOTAL (IN_C * HID_C + HID_C * OUT_C + HID_C + OUT_C)
__global__ void k_norm_w(const void* __restrict__ W0, const void* __restrict__ W1,
                         const void* __restrict__ b0, const void* __restrict__ b1,
                         const int* __restrict__ flags,
                         unsigned short* __restrict__ w0n, unsigned short* __restrict__ w1n,
                         float* __restrict__ b0n, float* __restrict__ b1n) {
    int mf = flags[0];
    int i = blockIdx.x * 256 + threadIdx.x;
    if (i >= NW_TOTAL) return;
    if (i < IN_C * HID_C) {
        w0n[i] = mf ? ((const unsigned short*)W0)[i] : f2bf(((const float*)W0)[i]);
    } else if (i < IN_C * HID_C + HID_C * OUT_C) {
        int j = i - IN_C * HID_C;
        w1n[j] = mf ? ((const unsigned short*)W1)[j] : f2bf(((const float*)W1)[j]);
    } else if (i < IN_C * HID_C + HID_C * OUT_C + HID_C) {
        int j = i - IN_C * HID_C - HID_C * OUT_C;
        b0n[j] = mf ? bf2f(((const unsigned short*)b0)[j]) : ((const float*)b0)[j];
    } else {
        int j = i - IN_C * HID_C - HID_C * OUT_C - HID_C;
        b1n[j] = mf ? bf2f(((const unsigned short*)b1)[j]) : ((const float*)b1)[j];
    }
}

// ---- Bucketed CSR build ----------------------------------------------------
__global__ __launch_bounds__(256) void k_part1(const int* __restrict__ ei,
                                               const int* __restrict__ flags,
                                               int* __restrict__ bcnt,
                                               int* __restrict__ block_off) {
    __shared__ int h[NBKT];
    int t = threadIdx.x;
    for (int i = t; i < NBKT; i += 256) h[i] = 0;
    __syncthreads();
    int mi = flags[1];
    int base = blockIdx.x * EPB;
    for (int j = t; j < EPB; j += 256) {
        int e = base + j;
        if (e < N_EDGES) atomicAdd(&h[load_dst(ei, mi, e) >> BSHIFT], 1);
    }
    __syncthreads();
    for (int i = t; i < NBKT; i += 256)
        block_off[blockIdx.x * NBKT + i] = atomicAdd(&bcnt[i], h[i]);
}

__global__ void k_scan_bkt(const int* __restrict__ bcnt, int* __restrict__ bbase) {
    __shared__ int sm[256];
    int t = threadIdx.x;
    int v = (t < NBKT) ? bcnt[t] : 0;
    sm[t] = v; __syncthreads();
    for (int off = 1; off < 256; off <<= 1) {
        int a = (t >= off) ? sm[t - off] : 0;
        __syncthreads();
        sm[t] += a;
        __syncthreads();
    }
    if (t < NBKT) bbase[t] = sm[t] - v;
    if (t == NBKT - 1) bbase[NBKT] = sm[t];
}

__global__ __launch_bounds__(256) void k_part2(const int* __restrict__ ei,
                                               const int* __restrict__ flags,
                                               const int* __restrict__ bbase,
                                               const int* __restrict__ block_off,
                                               unsigned int* __restrict__ bedges) {
    __shared__ int cur[NBKT];
    int t = threadIdx.x;
    for (int i = t; i < NBKT; i += 256)
        cur[i] = bbase[i] + block_off[blockIdx.x * NBKT + i];
    __syncthreads();
    int mi = flags[1];
    int base = blockIdx.x * EPB;
    for (int j = t; j < EPB; j += 256) {
        int e = base + j;
        if (e < N_EDGES) {
            int d = load_dst(ei, mi, e);
            int s = load_src(ei, mi, e);
            int p = atomicAdd(&cur[d >> BSHIFT], 1);
            bedges[p] = ((unsigned int)s << BSHIFT) | (unsigned int)(d & 511);
        }
    }
}

__global__ __launch_bounds__(512) void k_bucket_csr(const unsigned int* __restrict__ bedges,
                                                    const int* __restrict__ bbase,
                                                    int* __restrict__ rowptr,
                                                    float* __restrict__ dinv,
                                                    int* __restrict__ col) {
    __shared__ int cnt[512];
    __shared__ int cur[512];
    int b = blockIdx.x, t = threadIdx.x;
    int ebeg = bbase[b], eend = bbase[b + 1];
    cnt[t] = 0;
    __syncthreads();
    for (int j = ebeg + t; j < eend; j += 512)
        atomicAdd(&cnt[bedges[j] & 511], 1);
    __syncthreads();
    int v = cnt[t];
    cur[t] = v; __syncthreads();
    for (int off = 1; off < 512; off <<= 1) {
        int a = (t >= off) ? cur[t - off] : 0;
        __syncthreads();
        cur[t] += a;
        __syncthreads();
    }
    int excl = cur[t] - v;
    int node = b * 512 + t;
    if (node < N_NODES) {
        rowptr[node] = ebeg + excl;
        float dd = (float)v; if (dd < 1.f) dd = 1.f;
        dinv[node] = rsqrtf(dd);
    } else if (node == N_NODES) {
        rowptr[N_NODES] = ebeg + excl;  // == N_EDGES (no dst >= N_NODES exists)
    }
    __syncthreads();
    cur[t] = ebeg + excl;
    __syncthreads();
    for (int j = ebeg + t; j < eend; j += 512) {
        unsigned int pk = bedges[j];
        int p = atomicAdd(&cur[pk & 511], 1);
        col[p] = (int)(pk >> BSHIFT);
    }
}

// ============================================================================
// GEMM1: H1[N,128] = dinv[row] * (x[N,512] @ W0[128,512]^T)  (src-prescaled)
// async gload_lds, double-buffered, counted vmcnt(6) depth-2 pipeline.
// ============================================================================
#define G1_BUF 24576
#define G1_BOFF 16384

// ---- fp32-input fast path --------------------------------------------------
__device__ __forceinline__ void gemm1_f32_async(const float* __restrict__ xg,
                                                const unsigned short* __restrict__ w0n,
                                                const float* __restrict__ dinv,
                                                unsigned short* __restrict__ h1,
                                                char* __restrict__ smem,
                                                int node0, int t) {
    const int w = t >> 6;
    const int lane = t & 63;
    const int r16 = lane & 15;
    const int quad = lane >> 4;

    f32x4 acc[2][8];
#pragma unroll
    for (int m = 0; m < 2; m++)
#pragma unroll
        for (int c = 0; c < 8; c++) acc[m][c] = (f32x4){0.f, 0.f, 0.f, 0.f};

    const int lrow = lane >> 3;
    const int lch = (lane & 7) ^ lrow;
    const float* pa[4];
#pragma unroll
    for (int g = 0; g < 4; g++) {
        int r = node0 + w * 32 + 8 * g + lrow;
        if (r >= N_NODES) r = N_NODES - 1;
        pa[g] = xg + (size_t)r * IN_C + lch * 4;
    }
    const unsigned short* pb[2];
#pragma unroll
    for (int g = 0; g < 2; g++)
        pb[g] = w0n + (size_t)((2 * w + g) * 16 + r16) * IN_C + quad * 8;

    auto stage = [&](int buf, int ks) {
        char* Ab = smem + buf * G1_BUF + w * 4096;
        char* Bb = smem + buf * G1_BUF + G1_BOFF + w * 2048;
        glds16(pa[0] + ks, Ab);
        glds16(pa[1] + ks, Ab + 1024);
        glds16(pa[2] + ks, Ab + 2048);
        glds16(pa[3] + ks, Ab + 3072);
        glds16(pb[0] + ks, Bb);
        glds16(pb[1] + ks, Bb + 1024);
    };

    const int swz = r16 & 7;

    auto compute = [&](int buf) {
        const char* Ab = smem + buf * G1_BUF;
        const char* Bb = Ab + G1_BOFF;
        bf16x8 a[2];
#pragma unroll
        for (int m = 0; m < 2; m++) {
            int rowb = (w * 32 + m * 16 + r16) * 128;
            int c0 = ((2 * quad) ^ swz) * 16;
            int c1 = ((2 * quad + 1) ^ swz) * 16;
            float4 fa = *reinterpret_cast<const float4*>(Ab + rowb + c0);
            float4 fb = *reinterpret_cast<const float4*>(Ab + rowb + c1);
            a[m] = (bf16x8){(short)f2bf(fa.x), (short)f2bf(fa.y), (short)f2bf(fa.z), (short)f2bf(fa.w),
                            (short)f2bf(fb.x), (short)f2bf(fb.y), (short)f2bf(fb.z), (short)f2bf(fb.w)};
        }
#pragma unroll
        for (int ct = 0; ct < 8; ct++) {
            bf16x8 b = *reinterpret_cast<const bf16x8*>(Bb + ct * 1024 + lane * 16);
            acc[0][ct] = __builtin_amdgcn_mfma_f32_16x16x32_bf16(a[0], b, acc[0][ct], 0, 0, 0);
            acc[1][ct] = __builtin_amdgcn_mfma_f32_16x16x32_bf16(a[1], b, acc[1][ct], 0, 0, 0);
        }
    };

    stage(0, 0);
    stage(1, 32);
    for (int tt = 0; tt < 14; ++tt) {
        asm volatile("s_waitcnt vmcnt(6)" ::: "memory");
        __builtin_amdgcn_sched_barrier(0);
        __builtin_amdgcn_s_barrier();
        compute(tt & 1);
        __builtin_amdgcn_s_barrier();
        stage(tt & 1, (tt + 2) * 32);
    }
    asm volatile("s_waitcnt vmcnt(6)" ::: "memory");
    __builtin_amdgcn_sched_barrier(0);
    __builtin_amdgcn_s_barrier();
    compute(0);
    asm volatile("s_waitcnt vmcnt(0)" ::: "memory");
    __builtin_amdgcn_sched_barrier(0);
    __builtin_amdgcn_s_barrier();
    compute(1);

#pragma unroll
    for (int m = 0; m < 2; m++) {
#pragma unroll
        for (int r = 0; r < 4; r++) {
            int row = node0 + w * 32 + m * 16 + quad * 4 + r;
            if (row < N_NODES) {
                float dv = dinv[row];
#pragma unroll
                for (int ct = 0; ct < 8; ct++)
                    h1[(size_t)row * HID_C + ct * 16 + r16] = f2bf(acc[m][ct][r] * dv);
            }
        }
    }
}

// ---- bf16-input path (same layout, conservative drain0 loop) ---------------
__device__ __forceinline__ void gemm1_bf16_async(const unsigned short* __restrict__ xg,
                                                 const unsigned short* __restrict__ w0n,
                                                 const float* __restrict__ dinv,
                                                 unsigned short* __restrict__ h1,
                                                 unsigned short* __restrict__ smem,
                                                 int node0, int t) {
    const int w = t >> 6;
    const int lane = t & 63;
    const int r16 = lane & 15;
    const int quad = lane >> 4;

    f32x4 acc[2][8];
#pragma unroll
    for (int m = 0; m < 2; m++)
#pragma unroll
        for (int c = 0; c < 8; c++) acc[m][c] = (f32x4){0.f, 0.f, 0.f, 0.f};

    int rA0 = node0 + (2 * w) * 16 + r16;     if (rA0 >= N_NODES) rA0 = N_NODES - 1;
    int rA1 = node0 + (2 * w + 1) * 16 + r16; if (rA1 >= N_NODES) rA1 = N_NODES - 1;
    const unsigned short* pa0 = xg + (size_t)rA0 * IN_C + quad * 8;
    const unsigned short* pa1 = xg + (size_t)rA1 * IN_C + quad * 8;
    const unsigned short* pb0 = w0n + (size_t)((2 * w) * 16 + r16) * IN_C + quad * 8;
    const unsigned short* pb1 = w0n + (size_t)((2 * w + 1) * 16 + r16) * IN_C + quad * 8;

    auto stage = [&](int buf, int ks) {
        unsigned short* a = smem + buf * 8192 + (2 * w) * 512;
        glds16(pa0 + ks, a);
        glds16(pa1 + ks, a + 512);
        glds16(pb0 + ks, a + 4096);
        glds16(pb1 + ks, a + 4096 + 512);
    };

    const int fo = quad * 128 + r16 * 8;

    auto compute = [&](int buf) {
        const unsigned short* Ab = smem + buf * 8192;
        const unsigned short* Bb = Ab + 4096;
        bf16x8 a0 = *reinterpret_cast<const bf16x8*>(Ab + (2 * w) * 512 + fo);
        bf16x8 a1 = *reinterpret_cast<const bf16x8*>(Ab + (2 * w + 1) * 512 + fo);
#pragma unroll
        for (int ct = 0; ct < 8; ct++) {
            bf16x8 b = *reinterpret_cast<const bf16x8*>(Bb + ct * 512 + fo);
            acc[0][ct] = __builtin_amdgcn_mfma_f32_16x16x32_bf16(a0, b, acc[0][ct], 0, 0, 0);
            acc[1][ct] = __builtin_amdgcn_mfma_f32_16x16x32_bf16(a1, b, acc[1][ct], 0, 0, 0);
        }
    };

    stage(0, 0);
    __syncthreads();
    for (int tt = 0; tt < 15; ++tt) {
        int cur = tt & 1;
        stage(cur ^ 1, (tt + 1) * 32);
        compute(cur);
        __syncthreads();
    }
    compute(1);

#pragma unroll
    for (int m = 0; m < 2; m++) {
#pragma unroll
        for (int r = 0; r < 4; r++) {
            int row = node0 + w * 32 + m * 16 + quad * 4 + r;
            if (row < N_NODES) {
                float dv = dinv[row];
#pragma unroll
                for (int ct = 0; ct < 8; ct++)
                    h1[(size_t)row * HID_C + ct * 16 + r16] = f2bf(acc[m][ct][r] * dv);
            }
        }
    }
}

__global__ __launch_bounds__(256, 3) void k_gemm1(const void* __restrict__ x,
                                                  const unsigned short* __restrict__ w0n,
                                                  const int* __restrict__ flags,
                                                  const float* __restrict__ dinv,
                                                  unsigned short* __restrict__ h1) {
    __shared__ __align__(16) char smem[2 * G1_BUF];  // 49152 B -> 3 blocks/CU
    int node0 = blockIdx.x * 128;
    int t = threadIdx.x;
    if (flags[0]) gemm1_bf16_async((const unsigned short*)x, w0n, dinv, h1,
                                   (unsigned short*)smem, node0, t);
    else          gemm1_f32_async((const float*)x, w0n, dinv, h1, smem, node0, t);
}

// ---- Fused Agg1 (+bias+relu) + layer-2 projection --------------------------
// One wave per node: gather-sum prescaled h1 rows, bias+relu (fp32, never
// rounded), per-wave LDS h row, then lanes 0..39 compute
// p2[d][c] = dinv[d] * sum_k h[k]*W1[c][k].  h2 never materializes.
#define W1PAD 132   // fp32 row stride for W1 in LDS (mult of 4 for b128 reads)
__global__ __launch_bounds__(256) void k_agg1g2(const int* __restrict__ rowptr,
                                                const int* __restrict__ col,
                                                const float* __restrict__ dinv,
                                                const unsigned int* __restrict__ h1v,
                                                const float* __restrict__ b0n,
                                                const unsigned short* __restrict__ w1n,
                                                float* __restrict__ p2) {
    __shared__ float W1f[OUT_C][W1PAD];
    __shared__ float hrow[4][HID_C];
    int t = threadIdx.x;
    // stage W1 (bf16 -> fp32) once per block
    for (int i = t; i < OUT_C * HID_C; i += 256) {
        int c = i >> 7, k = i & 127;
        W1f[c][k] = bf2f(w1n[i]);
    }
    __syncthreads();

    int w = t >> 6;
    int lane = t & 63;
    int d = blockIdx.x * 4 + w;
    if (d >= N_NODES) return;
    int beg = rowptr[d], end = rowptr[d + 1];
    float a0 = 0.f, a1 = 0.f;
    for (int j0 = beg; j0 < end; j0 += 16) {
        int s[16];
        unsigned int r[16];
        float m[16];
#pragma unroll
        for (int q = 0; q < 16; q++) {
            int jj = j0 + q;
            int jc = jj < end ? jj : end - 1;   // clamp: always a valid edge of this row
            s[q] = col[jc];
            m[q] = jj < end ? 1.f : 0.f;
        }
#pragma unroll
        for (int q = 0; q < 16; q++) r[q] = h1v[(size_t)s[q] * 64 + lane];
#pragma unroll
        for (int q = 0; q < 16; q++) {
            a0 += m[q] * bf2f_lo(r[q]);
            a1 += m[q] * bf2f_hi(r[q]);
        }
    }
    float dv = dinv[d];
    float o0 = a0 * dv + b0n[2 * lane];
    float o1 = a1 * dv + b0n[2 * lane + 1];
    o0 = o0 > 0.f ? o0 : 0.f;
    o1 = o1 > 0.f ? o1 : 0.f;
    // per-wave LDS h row (fp32); within-wave ds ordering via lgkmcnt(0)
    *reinterpret_cast<float2*>(&hrow[w][2 * lane]) = (float2){o0, o1};
    asm volatile("s_waitcnt lgkmcnt(0)" ::: "memory");
    __builtin_amdgcn_sched_barrier(0);

    if (lane < OUT_C) {
        float accv = 0.f;
#pragma unroll
        for (int k0 = 0; k0 < HID_C; k0 += 4) {
            float4 hv = *reinterpret_cast<const float4*>(&hrow[w][k0]);      // broadcast
            float4 wv = *reinterpret_cast<const float4*>(&W1f[lane][k0]);
            accv += hv.x * wv.x + hv.y * wv.y + hv.z * wv.z + hv.w * wv.w;
        }
        p2[(size_t)d * OUT_C + lane] = accv * dv;   // prescale for agg2
    }
}

// ---- Agg layer 2 (+bias): masked 16-wide ILP batches, no serial tail -------
__global__ __launch_bounds__(256) void k_agg2(const int* __restrict__ rowptr,
                                              const int* __restrict__ col,
                                              const float* __restrict__ dinv,
                                              const float* __restrict__ p2,
                                              const float* __restrict__ b1n,
                                              const int* __restrict__ flags,
                                              void* __restrict__ out) {
    int w = threadIdx.x >> 6;
    int lane = threadIdx.x & 63;
    int d = blockIdx.x * 4 + w;
    if (d >= N_NODES || lane >= OUT_C) return;
    int beg = rowptr[d], end = rowptr[d + 1];
    float acc = 0.f;
    for (int j0 = beg; j0 < end; j0 += 16) {
        int s[16];
        float r[16];
        float m[16];
#pragma unroll
        for (int q = 0; q < 16; q++) {
            int jj = j0 + q;
            int jc = jj < end ? jj : end - 1;
            s[q] = col[jc];
            m[q] = jj < end ? 1.f : 0.f;
        }
#pragma unroll
        for (int q = 0; q < 16; q++) r[q] = p2[(size_t)s[q] * OUT_C + lane];
#pragma unroll
        for (int q = 0; q < 16; q++) acc += m[q] * r[q];
    }
    float v = acc * dinv[d] + b1n[lane];
    size_t idx = (size_t)d * OUT_C + lane;
    if (flags[0]) ((unsigned short*)out)[idx] = f2bf(v);
    else          ((float*)out)[idx] = v;
}

extern "C" void kernel_launch(void* const* d_in, const int* in_sizes, int n_in,
                              void* d_out, int out_size, void* d_ws, size_t ws_size,
                              hipStream_t stream) {
    const void* x  = d_in[0];
    const int* ei  = (const int*)d_in[1];
    const void* W0 = d_in[2];
    const void* b0 = d_in[3];
    const void* W1 = d_in[4];
    const void* b1 = d_in[5];

    char* ws = (char*)d_ws;
    size_t off = 0;
    auto alloc = [&](size_t bytes) {
        char* p = ws + off;
        off += (bytes + 511) & ~(size_t)511;
        return p;
    };
    // Total footprint ~58 MB.
    int*   flags   = (int*)  alloc(sizeof(int) * 2);
    int*   rowptr  = (int*)  alloc(sizeof(int) * (N_NODES + 1));
    float* dinv    = (float*)alloc(sizeof(float) * N_NODES);
    int*   col     = (int*)  alloc(sizeof(int) * N_EDGES);
    int*   bcnt    = (int*)  alloc(sizeof(int) * NBKT);
    int*   bbase   = (int*)  alloc(sizeof(int) * (NBKT + 1));
    int*   bloff   = (int*)  alloc(sizeof(int) * NPART * NBKT);
    unsigned int* bedges = (unsigned int*)alloc(sizeof(unsigned int) * N_EDGES);
    unsigned short* w0n = (unsigned short*)alloc(sizeof(unsigned short) * IN_C * HID_C);
    unsigned short* w1n = (unsigned short*)alloc(sizeof(unsigned short) * HID_C * OUT_C);
    float* b0n = (float*)alloc(sizeof(float) * HID_C);
    float* b1n = (float*)alloc(sizeof(float) * OUT_C);
    unsigned short* h1 = (unsigned short*)alloc(sizeof(unsigned short) * (size_t)N_NODES * HID_C);
    float* p2 = (float*)alloc(sizeof(float) * (size_t)N_NODES * OUT_C);

    k_detect<<<1, 64, 0, stream>>>((const unsigned int*)x, ei, flags);
    k_norm_w<<<(NW_TOTAL + 255) / 256, 256, 0, stream>>>(W0, W1, b0, b1, flags, w0n, w1n, b0n, b1n);

    hipMemsetAsync(bcnt, 0, sizeof(int) * NBKT, stream);
    k_part1<<<NPART, 256, 0, stream>>>(ei, flags, bcnt, bloff);
    k_scan_bkt<<<1, 256, 0, stream>>>(bcnt, bbase);
    k_part2<<<NPART, 256, 0, stream>>>(ei, flags, bbase, bloff, bedges);
    k_bucket_csr<<<NBKT, 512, 0, stream>>>(bedges, bbase, rowptr, dinv, col);

    k_gemm1<<<(N_NODES + 127) / 128, 256, 0, stream>>>(x, w0n, flags, dinv, h1);
    k_agg1g2<<<(N_NODES + 3) / 4, 256, 0, stream>>>(rowptr, col, dinv,
                                                    (const unsigned int*)h1, b0n,
                                                    w1n, p2);
    k_agg2<<<(N_NODES + 3) / 4, 256, 0, stream>>>(rowptr, col, dinv, p2, b1n, flags, d_out);
}

// Round 6
// 503.076 us; speedup vs baseline: 1.0987x; 1.0987x over previous
//
#include <hip/hip_runtime.h>
#include <hip/hip_bf16.h>
#include <cstddef>

#define N_NODES 100000
#define N_EDGES 1600000
#define IN_C 512
#define HID_C 128
#define OUT_C 40
#define OUT_CP 48   // padded col count for MFMA (3 x 16)
#define EPB 8000    // edges per partition block
#define NPART 200   // ceil(N_EDGES / EPB)
#define NBKT 196    // buckets of 512 nodes (dst >> 9); 99999>>9 = 195
#define BSHIFT 9

typedef short bf16x8 __attribute__((ext_vector_type(8)));
typedef float f32x4 __attribute__((ext_vector_type(4)));

__device__ __forceinline__ float bf2f(unsigned short u) {
    union { unsigned int i; float f; } v; v.i = ((unsigned int)u) << 16; return v.f;
}
__device__ __forceinline__ float bf2f_lo(unsigned int u) {
    union { unsigned int i; float f; } v; v.i = u << 16; return v.f;
}
__device__ __forceinline__ float bf2f_hi(unsigned int u) {
    union { unsigned int i; float f; } v; v.i = u & 0xFFFF0000u; return v.f;
}
__device__ __forceinline__ unsigned short f2bf(float f) {
    union { float f; unsigned int i; } v; v.f = f;
    unsigned int x = v.i;
    return (unsigned short)((x + 0x7FFFu + ((x >> 16) & 1u)) >> 16);  // RNE
}

// async 16B global -> LDS (wave-uniform LDS base + lane*16 dest; per-lane global src)
__device__ __forceinline__ void glds16(const void* g, void* l) {
    __builtin_amdgcn_global_load_lds(
        (const __attribute__((address_space(1))) unsigned int*)g,
        (__attribute__((address_space(3))) unsigned int*)l,
        16, 0, 0);
}

// ---- dtype detection -------------------------------------------------------
__global__ void k_detect(const unsigned int* __restrict__ xbits,
                         const int* __restrict__ ei32, int* __restrict__ flags) {
    if (threadIdx.x == 0 && blockIdx.x == 0) {
        int inrange = 0;
        for (int i = 0; i < 64; i++) {
            unsigned int b = xbits[i * 33 + 1];
            int e = (int)((b >> 23) & 0xFFu);
            if (e >= 90 && e <= 160) inrange++;
        }
        flags[0] = (inrange >= 32) ? 0 : 1;
        int zeros = 0;
        for (int i = 0; i < 8; i++) if (ei32[2 * i + 1] == 0) zeros++;
        flags[1] = (zeros == 8) ? 1 : 0;
    }
}

__device__ __forceinline__ int load_src(const int* ei, int mi, int e) {
    return mi ? ei[2 * e] : ei[e];
}
__device__ __forceinline__ int load_dst(const int* ei, int mi, int e) {
    return mi ? ei[2 * (N_EDGES + e)] : ei[N_EDGES + e];
}

// ---- weight/bias normalization ---------------------------------------------
#define NW_TOTAL (IN_C * HID_C + HID_C * OUT_C + HID_C + OUT_C)
__global__ void k_norm_w(const void* __restrict__ W0, const void* __restrict__ W1,
                         const void* __restrict__ b0, const void* __restrict__ b1,
                         const int* __restrict__ flags,
                         unsigned short* __restrict__ w0n, unsigned short* __restrict__ w1n,
                         float* __restrict__ b0n, float* __restrict__ b1n) {
    int mf = flags[0];
    int i = blockIdx.x * 256 + threadIdx.x;
    if (i >= NW_TOTAL) return;
    if (i < IN_C * HID_C) {
        w0n[i] = mf ? ((const unsigned short*)W0)[i] : f2bf(((const float*)W0)[i]);
    } else if (i < IN_C * HID_C + HID_C * OUT_C) {
        int j = i - IN_C * HID_C;
        w1n[j] = mf ? ((const unsigned short*)W1)[j] : f2bf(((const float*)W1)[j]);
    } else if (i < IN_C * HID_C + HID_C * OUT_C + HID_C) {
        int j = i - IN_C * HID_C - HID_C * OUT_C;
        b0n[j] = mf ? bf2f(((const unsigned short*)b0)[j]) : ((const float*)b0)[j];
    } else {
        int j = i - IN_C * HID_C - HID_C * OUT_C - HID_C;
        b1n[j] = mf ? bf2f(((const unsigned short*)b1)[j]) : ((const float*)b1)[j];
    }
}

// ---- Bucketed CSR build ----------------------------------------------------
__global__ __launch_bounds__(256) void k_part1(const int* __restrict__ ei,
                                               const int* __restrict__ flags,
                                               int* __restrict__ bcnt,
                                               int* __restrict__ block_off) {
    __shared__ int h[NBKT];
    int t = threadIdx.x;
    for (int i = t; i < NBKT; i += 256) h[i] = 0;
    __syncthreads();
    int mi = flags[1];
    int base = blockIdx.x * EPB;
    for (int j = t; j < EPB; j += 256) {
        int e = base + j;
        if (e < N_EDGES) atomicAdd(&h[load_dst(ei, mi, e) >> BSHIFT], 1);
    }
    __syncthreads();
    for (int i = t; i < NBKT; i += 256)
        block_off[blockIdx.x * NBKT + i] = atomicAdd(&bcnt[i], h[i]);
}

__global__ void k_scan_bkt(const int* __restrict__ bcnt, int* __restrict__ bbase) {
    __shared__ int sm[256];
    int t = threadIdx.x;
    int v = (t < NBKT) ? bcnt[t] : 0;
    sm[t] = v; __syncthreads();
    for (int off = 1; off < 256; off <<= 1) {
        int a = (t >= off) ? sm[t - off] : 0;
        __syncthreads();
        sm[t] += a;
        __syncthreads();
    }
    if (t < NBKT) bbase[t] = sm[t] - v;
    if (t == NBKT - 1) bbase[NBKT] = sm[t];
}

__global__ __launch_bounds__(256) void k_part2(const int* __restrict__ ei,
                                               const int* __restrict__ flags,
                                               const int* __restrict__ bbase,
                                               const int* __restrict__ block_off,
                                               unsigned int* __restrict__ bedges) {
    __shared__ int cur[NBKT];
    int t = threadIdx.x;
    for (int i = t; i < NBKT; i += 256)
        cur[i] = bbase[i] + block_off[blockIdx.x * NBKT + i];
    __syncthreads();
    int mi = flags[1];
    int base = blockIdx.x * EPB;
    for (int j = t; j < EPB; j += 256) {
        int e = base + j;
        if (e < N_EDGES) {
            int d = load_dst(ei, mi, e);
            int s = load_src(ei, mi, e);
            int p = atomicAdd(&cur[d >> BSHIFT], 1);
            bedges[p] = ((unsigned int)s << BSHIFT) | (unsigned int)(d & 511);
        }
    }
}

__global__ __launch_bounds__(512) void k_bucket_csr(const unsigned int* __restrict__ bedges,
                                                    const int* __restrict__ bbase,
                                                    int* __restrict__ rowptr,
                                                    float* __restrict__ dinv,
                                                    int* __restrict__ col) {
    __shared__ int cnt[512];
    __shared__ int cur[512];
    int b = blockIdx.x, t = threadIdx.x;
    int ebeg = bbase[b], eend = bbase[b + 1];
    cnt[t] = 0;
    __syncthreads();
    for (int j = ebeg + t; j < eend; j += 512)
        atomicAdd(&cnt[bedges[j] & 511], 1);
    __syncthreads();
    int v = cnt[t];
    cur[t] = v; __syncthreads();
    for (int off = 1; off < 512; off <<= 1) {
        int a = (t >= off) ? cur[t - off] : 0;
        __syncthreads();
        cur[t] += a;
        __syncthreads();
    }
    int excl = cur[t] - v;
    int node = b * 512 + t;
    if (node < N_NODES) {
        rowptr[node] = ebeg + excl;
        float dd = (float)v; if (dd < 1.f) dd = 1.f;
        dinv[node] = rsqrtf(dd);
    } else if (node == N_NODES) {
        rowptr[N_NODES] = ebeg + excl;  // == N_EDGES (no dst >= N_NODES exists)
    }
    __syncthreads();
    cur[t] = ebeg + excl;
    __syncthreads();
    for (int j = ebeg + t; j < eend; j += 512) {
        unsigned int pk = bedges[j];
        int p = atomicAdd(&cur[pk & 511], 1);
        col[p] = (int)(pk >> BSHIFT);
    }
}

// ============================================================================
// GEMM1: H1[N,128] = dinv[row] * (x[N,512] @ W0[128,512]^T)  (src-prescaled)
// async gload_lds, double-buffered, counted vmcnt(6) depth-2 pipeline.
// ============================================================================
#define G1_BUF 24576
#define G1_BOFF 16384

// ---- fp32-input fast path --------------------------------------------------
__device__ __forceinline__ void gemm1_f32_async(const float* __restrict__ xg,
                                                const unsigned short* __restrict__ w0n,
                                                const float* __restrict__ dinv,
                                                unsigned short* __restrict__ h1,
                                                char* __restrict__ smem,
                                                int node0, int t) {
    const int w = t >> 6;
    const int lane = t & 63;
    const int r16 = lane & 15;
    const int quad = lane >> 4;

    f32x4 acc[2][8];
#pragma unroll
    for (int m = 0; m < 2; m++)
#pragma unroll
        for (int c = 0; c < 8; c++) acc[m][c] = (f32x4){0.f, 0.f, 0.f, 0.f};

    const int lrow = lane >> 3;
    const int lch = (lane & 7) ^ lrow;
    const float* pa[4];
#pragma unroll
    for (int g = 0; g < 4; g++) {
        int r = node0 + w * 32 + 8 * g + lrow;
        if (r >= N_NODES) r = N_NODES - 1;
        pa[g] = xg + (size_t)r * IN_C + lch * 4;
    }
    const unsigned short* pb[2];
#pragma unroll
    for (int g = 0; g < 2; g++)
        pb[g] = w0n + (size_t)((2 * w + g) * 16 + r16) * IN_C + quad * 8;

    auto stage = [&](int buf, int ks) {
        char* Ab = smem + buf * G1_BUF + w * 4096;
        char* Bb = smem + buf * G1_BUF + G1_BOFF + w * 2048;
        glds16(pa[0] + ks, Ab);
        glds16(pa[1] + ks, Ab + 1024);
        glds16(pa[2] + ks, Ab + 2048);
        glds16(pa[3] + ks, Ab + 3072);
        glds16(pb[0] + ks, Bb);
        glds16(pb[1] + ks, Bb + 1024);
    };

    const int swz = r16 & 7;

    auto compute = [&](int buf) {
        const char* Ab = smem + buf * G1_BUF;
        const char* Bb = Ab + G1_BOFF;
        bf16x8 a[2];
#pragma unroll
        for (int m = 0; m < 2; m++) {
            int rowb = (w * 32 + m * 16 + r16) * 128;
            int c0 = ((2 * quad) ^ swz) * 16;
            int c1 = ((2 * quad + 1) ^ swz) * 16;
            float4 fa = *reinterpret_cast<const float4*>(Ab + rowb + c0);
            float4 fb = *reinterpret_cast<const float4*>(Ab + rowb + c1);
            a[m] = (bf16x8){(short)f2bf(fa.x), (short)f2bf(fa.y), (short)f2bf(fa.z), (short)f2bf(fa.w),
                            (short)f2bf(fb.x), (short)f2bf(fb.y), (short)f2bf(fb.z), (short)f2bf(fb.w)};
        }
#pragma unroll
        for (int ct = 0; ct < 8; ct++) {
            bf16x8 b = *reinterpret_cast<const bf16x8*>(Bb + ct * 1024 + lane * 16);
            acc[0][ct] = __builtin_amdgcn_mfma_f32_16x16x32_bf16(a[0], b, acc[0][ct], 0, 0, 0);
            acc[1][ct] = __builtin_amdgcn_mfma_f32_16x16x32_bf16(a[1], b, acc[1][ct], 0, 0, 0);
        }
    };

    stage(0, 0);
    stage(1, 32);
    for (int tt = 0; tt < 14; ++tt) {
        asm volatile("s_waitcnt vmcnt(6)" ::: "memory");
        __builtin_amdgcn_sched_barrier(0);
        __builtin_amdgcn_s_barrier();
        compute(tt & 1);
        __builtin_amdgcn_s_barrier();
        stage(tt & 1, (tt + 2) * 32);
    }
    asm volatile("s_waitcnt vmcnt(6)" ::: "memory");
    __builtin_amdgcn_sched_barrier(0);
    __builtin_amdgcn_s_barrier();
    compute(0);
    asm volatile("s_waitcnt vmcnt(0)" ::: "memory");
    __builtin_amdgcn_sched_barrier(0);
    __builtin_amdgcn_s_barrier();
    compute(1);

#pragma unroll
    for (int m = 0; m < 2; m++) {
#pragma unroll
        for (int r = 0; r < 4; r++) {
            int row = node0 + w * 32 + m * 16 + quad * 4 + r;
            if (row < N_NODES) {
                float dv = dinv[row];
#pragma unroll
                for (int ct = 0; ct < 8; ct++)
                    h1[(size_t)row * HID_C + ct * 16 + r16] = f2bf(acc[m][ct][r] * dv);
            }
        }
    }
}

// ---- bf16-input path (same layout, conservative drain0 loop) ---------------
__device__ __forceinline__ void gemm1_bf16_async(const unsigned short* __restrict__ xg,
                                                 const unsigned short* __restrict__ w0n,
                                                 const float* __restrict__ dinv,
                                                 unsigned short* __restrict__ h1,
                                                 unsigned short* __restrict__ smem,
                                                 int node0, int t) {
    const int w = t >> 6;
    const int lane = t & 63;
    const int r16 = lane & 15;
    const int quad = lane >> 4;

    f32x4 acc[2][8];
#pragma unroll
    for (int m = 0; m < 2; m++)
#pragma unroll
        for (int c = 0; c < 8; c++) acc[m][c] = (f32x4){0.f, 0.f, 0.f, 0.f};

    int rA0 = node0 + (2 * w) * 16 + r16;     if (rA0 >= N_NODES) rA0 = N_NODES - 1;
    int rA1 = node0 + (2 * w + 1) * 16 + r16; if (rA1 >= N_NODES) rA1 = N_NODES - 1;
    const unsigned short* pa0 = xg + (size_t)rA0 * IN_C + quad * 8;
    const unsigned short* pa1 = xg + (size_t)rA1 * IN_C + quad * 8;
    const unsigned short* pb0 = w0n + (size_t)((2 * w) * 16 + r16) * IN_C + quad * 8;
    const unsigned short* pb1 = w0n + (size_t)((2 * w + 1) * 16 + r16) * IN_C + quad * 8;

    auto stage = [&](int buf, int ks) {
        unsigned short* a = smem + buf * 8192 + (2 * w) * 512;
        glds16(pa0 + ks, a);
        glds16(pa1 + ks, a + 512);
        glds16(pb0 + ks, a + 4096);
        glds16(pb1 + ks, a + 4096 + 512);
    };

    const int fo = quad * 128 + r16 * 8;

    auto compute = [&](int buf) {
        const unsigned short* Ab = smem + buf * 8192;
        const unsigned short* Bb = Ab + 4096;
        bf16x8 a0 = *reinterpret_cast<const bf16x8*>(Ab + (2 * w) * 512 + fo);
        bf16x8 a1 = *reinterpret_cast<const bf16x8*>(Ab + (2 * w + 1) * 512 + fo);
#pragma unroll
        for (int ct = 0; ct < 8; ct++) {
            bf16x8 b = *reinterpret_cast<const bf16x8*>(Bb + ct * 512 + fo);
            acc[0][ct] = __builtin_amdgcn_mfma_f32_16x16x32_bf16(a0, b, acc[0][ct], 0, 0, 0);
            acc[1][ct] = __builtin_amdgcn_mfma_f32_16x16x32_bf16(a1, b, acc[1][ct], 0, 0, 0);
        }
    };

    stage(0, 0);
    __syncthreads();
    for (int tt = 0; tt < 15; ++tt) {
        int cur = tt & 1;
        stage(cur ^ 1, (tt + 1) * 32);
        compute(cur);
        __syncthreads();
    }
    compute(1);

#pragma unroll
    for (int m = 0; m < 2; m++) {
#pragma unroll
        for (int r = 0; r < 4; r++) {
            int row = node0 + w * 32 + m * 16 + quad * 4 + r;
            if (row < N_NODES) {
                float dv = dinv[row];
#pragma unroll
                for (int ct = 0; ct < 8; ct++)
                    h1[(size_t)row * HID_C + ct * 16 + r16] = f2bf(acc[m][ct][r] * dv);
            }
        }
    }
}

__global__ __launch_bounds__(256, 3) void k_gemm1(const void* __restrict__ x,
                                                  const unsigned short* __restrict__ w0n,
                                                  const int* __restrict__ flags,
                                                  const float* __restrict__ dinv,
                                                  unsigned short* __restrict__ h1) {
    __shared__ __align__(16) char smem[2 * G1_BUF];  // 49152 B -> 3 blocks/CU
    int node0 = blockIdx.x * 128;
    int t = threadIdx.x;
    if (flags[0]) gemm1_bf16_async((const unsigned short*)x, w0n, dinv, h1,
                                   (unsigned short*)smem, node0, t);
    else          gemm1_f32_async((const float*)x, w0n, dinv, h1, smem, node0, t);
}

// ---- Agg layer 1 (+bias+relu): scalarized col path, masked 16-wide ---------
// beg/end forced to SGPR via readfirstlane -> jc/col[jc]/mask are uniform:
// col via s_load, clamp/mask via SALU (co-issued), gather via uniform-base
// global_load with constant lane*4 voffset. VALU/edge = 2 unpack + 2 fmac.
__global__ __launch_bounds__(256) void k_agg1(const int* __restrict__ rowptr,
                                              const int* __restrict__ col,
                                              const float* __restrict__ dinv,
                                              const unsigned int* __restrict__ h1v,
                                              const float* __restrict__ b0n,
                                              unsigned int* __restrict__ h2v) {
    int w = threadIdx.x >> 6;
    int lane = threadIdx.x & 63;
    int d = blockIdx.x * 4 + w;
    if (d >= N_NODES) return;
    int beg = __builtin_amdgcn_readfirstlane(rowptr[d]);
    int end = __builtin_amdgcn_readfirstlane(rowptr[d + 1]);
    float a0 = 0.f, a1 = 0.f;
    for (int j0 = beg; j0 < end; j0 += 16) {
        int s[16];
        float m[16];
#pragma unroll
        for (int q = 0; q < 16; q++) {
            int jj = j0 + q;
            int jc = jj < end ? jj : end - 1;  // uniform -> SALU cselect
            s[q] = col[jc];                    // uniform addr -> s_load
            m[q] = jj < end ? 1.f : 0.f;       // uniform -> SGPR float
        }
        unsigned int r[16];
#pragma unroll
        for (int q = 0; q < 16; q++) {
            const unsigned int* rp = h1v + (size_t)s[q] * 64;  // uniform base
            r[q] = rp[lane];
        }
#pragma unroll
        for (int q = 0; q < 16; q++) {
            a0 += m[q] * bf2f_lo(r[q]);
            a1 += m[q] * bf2f_hi(r[q]);
        }
    }
    float dv = dinv[d];
    float o0 = a0 * dv + b0n[2 * lane];
    float o1 = a1 * dv + b0n[2 * lane + 1];
    o0 = o0 > 0.f ? o0 : 0.f;
    o1 = o1 > 0.f ? o1 : 0.f;
    h2v[(size_t)d * 64 + lane] = (unsigned int)f2bf(o0) | ((unsigned int)f2bf(o1) << 16);
}

// ---- GEMM2 (MFMA): P2[N,40] = dinv[row] * (H2[N,128] @ W1p[48,128]^T) ------
__global__ __launch_bounds__(256) void k_gemm2(const unsigned short* __restrict__ h2,
                                               const unsigned short* __restrict__ w1p,
                                               const float* __restrict__ dinv,
                                               float* __restrict__ p2) {
    int wave = (blockIdx.x * 256 + (int)threadIdx.x) >> 6;
    if (wave >= N_NODES / 16) return;
    int lane = threadIdx.x & 63;
    int r16 = lane & 15;
    int quad = lane >> 4;
    int node_base = wave * 16;

    f32x4 acc[3];
#pragma unroll
    for (int c = 0; c < 3; c++) acc[c] = (f32x4){0.f, 0.f, 0.f, 0.f};

    const unsigned short* arow = h2 + (size_t)(node_base + r16) * HID_C + quad * 8;
    const unsigned short* brow = w1p + (size_t)r16 * HID_C + quad * 8;

#pragma unroll
    for (int k0 = 0; k0 < HID_C; k0 += 32) {
        bf16x8 a = *reinterpret_cast<const bf16x8*>(arow + k0);
#pragma unroll
        for (int ct = 0; ct < 3; ct++) {
            bf16x8 b = *reinterpret_cast<const bf16x8*>(brow + (size_t)ct * 16 * HID_C + k0);
            acc[ct] = __builtin_amdgcn_mfma_f32_16x16x32_bf16(a, b, acc[ct], 0, 0, 0);
        }
    }

    float dv[4];
#pragma unroll
    for (int r = 0; r < 4; r++) dv[r] = dinv[node_base + quad * 4 + r];

#pragma unroll
    for (int ct = 0; ct < 3; ct++) {
        int chan = ct * 16 + r16;
        if (chan < OUT_C) {
#pragma unroll
            for (int r = 0; r < 4; r++) {
                p2[(size_t)(node_base + quad * 4 + r) * OUT_C + chan] = acc[ct][r] * dv[r];
            }
        }
    }
}

// ---- Agg layer 2 (+bias): scalarized col path, masked 16-wide --------------
__global__ __launch_bounds__(256) void k_agg2(const int* __restrict__ rowptr,
                                              const int* __restrict__ col,
                                              const float* __restrict__ dinv,
                                              const float* __restrict__ p2,
                                              const float* __restrict__ b1n,
                                              const int* __restrict__ flags,
                                              void* __restrict__ out) {
    int w = threadIdx.x >> 6;
    int lane = threadIdx.x & 63;
    int d = blockIdx.x * 4 + w;
    if (d >= N_NODES || lane >= OUT_C) return;
    int beg = __builtin_amdgcn_readfirstlane(rowptr[d]);
    int end = __builtin_amdgcn_readfirstlane(rowptr[d + 1]);
    float acc = 0.f;
    for (int j0 = beg; j0 < end; j0 += 16) {
        int s[16];
        float m[16];
#pragma unroll
        for (int q = 0; q < 16; q++) {
            int jj = j0 + q;
            int jc = jj < end ? jj : end - 1;
            s[q] = col[jc];                    // uniform -> s_load
            m[q] = jj < end ? 1.f : 0.f;
        }
        float r[16];
#pragma unroll
        for (int q = 0; q < 16; q++) {
            const float* rp = p2 + (size_t)s[q] * OUT_C;       // uniform base
            r[q] = rp[lane];
        }
#pragma unroll
        for (int q = 0; q < 16; q++) acc += m[q] * r[q];
    }
    float v = acc * dinv[d] + b1n[lane];
    size_t idx = (size_t)d * OUT_C + lane;
    if (flags[0]) ((unsigned short*)out)[idx] = f2bf(v);
    else          ((float*)out)[idx] = v;
}

extern "C" void kernel_launch(void* const* d_in, const int* in_sizes, int n_in,
                              void* d_out, int out_size, void* d_ws, size_t ws_size,
                              hipStream_t stream) {
    const void* x  = d_in[0];
    const int* ei  = (const int*)d_in[1];
    const void* W0 = d_in[2];
    const void* b0 = d_in[3];
    const void* W1 = d_in[4];
    const void* b1 = d_in[5];

    char* ws = (char*)d_ws;
    size_t off = 0;
    auto alloc = [&](size_t bytes) {
        char* p = ws + off;
        off += (bytes + 511) & ~(size_t)511;
        return p;
    };
    // Total footprint ~66 MB.
    int*   flags   = (int*)  alloc(sizeof(int) * 2);
    int*   rowptr  = (int*)  alloc(sizeof(int) * (N_NODES + 1));
    float* dinv    = (float*)alloc(sizeof(float) * N_NODES);
    int*   col     = (int*)  alloc(sizeof(int) * N_EDGES);
    int*   bcnt    = (int*)  alloc(sizeof(int) * NBKT);
    int*   bbase   = (int*)  alloc(sizeof(int) * (NBKT + 1));
    int*   bloff   = (int*)  alloc(sizeof(int) * NPART * NBKT);
    unsigned int* bedges = (unsigned int*)alloc(sizeof(unsigned int) * N_EDGES);
    unsigned short* w0n = (unsigned short*)alloc(sizeof(unsigned short) * IN_C * HID_C);
    unsigned short* w1n = (unsigned short*)alloc(sizeof(unsigned short) * OUT_CP * HID_C);
    float* b0n = (float*)alloc(sizeof(float) * HID_C);
    float* b1n = (float*)alloc(sizeof(float) * OUT_C);
    unsigned short* h1 = (unsigned short*)alloc(sizeof(unsigned short) * (size_t)N_NODES * HID_C);
    unsigned short* h2 = (unsigned short*)alloc(sizeof(unsigned short) * (size_t)N_NODES * HID_C);
    float* p2 = (float*)h1;  // h1 dead after k_agg1; 16 MB fits inside h1's 25.6 MB

    k_detect<<<1, 64, 0, stream>>>((const unsigned int*)x, ei, flags);
    hipMemsetAsync(w1n, 0, sizeof(unsigned short) * OUT_CP * HID_C, stream);
    k_norm_w<<<(NW_TOTAL + 255) / 256, 256, 0, stream>>>(W0, W1, b0, b1, flags, w0n, w1n, b0n, b1n);

    hipMemsetAsync(bcnt, 0, sizeof(int) * NBKT, stream);
    k_part1<<<NPART, 256, 0, stream>>>(ei, flags, bcnt, bloff);
    k_scan_bkt<<<1, 256, 0, stream>>>(bcnt, bbase);
    k_part2<<<NPART, 256, 0, stream>>>(ei, flags, bbase, bloff, bedges);
    k_bucket_csr<<<NBKT, 512, 0, stream>>>(bedges, bbase, rowptr, dinv, col);

    k_gemm1<<<(N_NODES + 127) / 128, 256, 0, stream>>>(x, w0n, flags, dinv, h1);
    k_agg1<<<(N_NODES + 3) / 4, 256, 0, stream>>>(rowptr, col, dinv,
                                                  (const unsigned int*)h1, b0n,
                                                  (unsigned int*)h2);
    k_gemm2<<<(N_NODES / 16 + 3) / 4, 256, 0, stream>>>(h2, w1n, dinv, p2);
    k_agg2<<<(N_NODES + 3) / 4, 256, 0, stream>>>(rowptr, col, dinv, p2, b1n, flags, d_out);
}

// Round 7
// 493.414 us; speedup vs baseline: 1.1202x; 1.0196x over previous
//
#include <hip/hip_runtime.h>
#include <hip/hip_bf16.h>
#include <cstddef>

#define N_NODES 100000
#define N_EDGES 1600000
#define IN_C 512
#define HID_C 128
#define OUT_C 40
#define OUT_CP 48   // padded col count for MFMA (3 x 16)
#define EPB 8000    // edges per partition block
#define NPART 200   // ceil(N_EDGES / EPB)
#define NBKT 196    // buckets of 512 nodes (dst >> 9); 99999>>9 = 195
#define BSHIFT 9

typedef short bf16x8 __attribute__((ext_vector_type(8)));
typedef float f32x4 __attribute__((ext_vector_type(4)));

__device__ __forceinline__ float bf2f(unsigned short u) {
    union { unsigned int i; float f; } v; v.i = ((unsigned int)u) << 16; return v.f;
}
__device__ __forceinline__ float bf2f_lo(unsigned int u) {
    union { unsigned int i; float f; } v; v.i = u << 16; return v.f;
}
__device__ __forceinline__ float bf2f_hi(unsigned int u) {
    union { unsigned int i; float f; } v; v.i = u & 0xFFFF0000u; return v.f;
}
__device__ __forceinline__ unsigned short f2bf(float f) {
    union { float f; unsigned int i; } v; v.f = f;
    unsigned int x = v.i;
    return (unsigned short)((x + 0x7FFFu + ((x >> 16) & 1u)) >> 16);  // RNE
}

// async 16B global -> LDS (wave-uniform LDS base + lane*16 dest; per-lane global src)
__device__ __forceinline__ void glds16(const void* g, void* l) {
    __builtin_amdgcn_global_load_lds(
        (const __attribute__((address_space(1))) unsigned int*)g,
        (__attribute__((address_space(3))) unsigned int*)l,
        16, 0, 0);
}

// ---- dtype detection (one wave, ballot) ------------------------------------
__global__ void k_detect(const unsigned int* __restrict__ xbits,
                         const int* __restrict__ ei32, int* __restrict__ flags) {
    int lane = threadIdx.x & 63;
    unsigned int b = xbits[lane * 33 + 1];
    int e = (int)((b >> 23) & 0xFFu);
    unsigned long long bal = __ballot(e >= 90 && e <= 160);
    int zpred = (lane < 8) ? (ei32[2 * lane + 1] == 0) : 0;
    unsigned long long zb = __ballot(zpred);
    if (lane == 0) {
        flags[0] = (__popcll(bal) >= 32) ? 0 : 1;
        flags[1] = ((zb & 0xFFull) == 0xFFull) ? 1 : 0;
    }
}

__device__ __forceinline__ int load_src(const int* ei, int mi, int e) {
    return mi ? ei[2 * e] : ei[e];
}
__device__ __forceinline__ int load_dst(const int* ei, int mi, int e) {
    return mi ? ei[2 * (N_EDGES + e)] : ei[N_EDGES + e];
}

// ---- weight/bias normalization ---------------------------------------------
#define NW_TOTAL (IN_C * HID_C + HID_C * OUT_C + HID_C + OUT_C)
__global__ void k_norm_w(const void* __restrict__ W0, const void* __restrict__ W1,
                         const void* __restrict__ b0, const void* __restrict__ b1,
                         const int* __restrict__ flags,
                         unsigned short* __restrict__ w0n, unsigned short* __restrict__ w1n,
                         float* __restrict__ b0n, float* __restrict__ b1n) {
    int mf = flags[0];
    int i = blockIdx.x * 256 + threadIdx.x;
    if (i >= NW_TOTAL) return;
    if (i < IN_C * HID_C) {
        w0n[i] = mf ? ((const unsigned short*)W0)[i] : f2bf(((const float*)W0)[i]);
    } else if (i < IN_C * HID_C + HID_C * OUT_C) {
        int j = i - IN_C * HID_C;
        w1n[j] = mf ? ((const unsigned short*)W1)[j] : f2bf(((const float*)W1)[j]);
    } else if (i < IN_C * HID_C + HID_C * OUT_C + HID_C) {
        int j = i - IN_C * HID_C - HID_C * OUT_C;
        b0n[j] = mf ? bf2f(((const unsigned short*)b0)[j]) : ((const float*)b0)[j];
    } else {
        int j = i - IN_C * HID_C - HID_C * OUT_C - HID_C;
        b1n[j] = mf ? bf2f(((const unsigned short*)b1)[j]) : ((const float*)b1)[j];
    }
}

// ---- Bucketed CSR build ----------------------------------------------------
__global__ __launch_bounds__(256) void k_part1(const int* __restrict__ ei,
                                               const int* __restrict__ flags,
                                               int* __restrict__ bcnt,
                                               int* __restrict__ block_off) {
    __shared__ int h[NBKT];
    int t = threadIdx.x;
    for (int i = t; i < NBKT; i += 256) h[i] = 0;
    __syncthreads();
    int mi = flags[1];
    int base = blockIdx.x * EPB;
    for (int j = t; j < EPB; j += 256) {
        int e = base + j;
        if (e < N_EDGES) atomicAdd(&h[load_dst(ei, mi, e) >> BSHIFT], 1);
    }
    __syncthreads();
    for (int i = t; i < NBKT; i += 256)
        block_off[blockIdx.x * NBKT + i] = atomicAdd(&bcnt[i], h[i]);
}

__global__ void k_scan_bkt(const int* __restrict__ bcnt, int* __restrict__ bbase) {
    __shared__ int sm[256];
    int t = threadIdx.x;
    int v = (t < NBKT) ? bcnt[t] : 0;
    sm[t] = v; __syncthreads();
    for (int off = 1; off < 256; off <<= 1) {
        int a = (t >= off) ? sm[t - off] : 0;
        __syncthreads();
        sm[t] += a;
        __syncthreads();
    }
    if (t < NBKT) bbase[t] = sm[t] - v;
    if (t == NBKT - 1) bbase[NBKT] = sm[t];
}

__global__ __launch_bounds__(256) void k_part2(const int* __restrict__ ei,
                                               const int* __restrict__ flags,
                                               const int* __restrict__ bbase,
                                               const int* __restrict__ block_off,
                                               unsigned int* __restrict__ bedges) {
    __shared__ int cur[NBKT];
    int t = threadIdx.x;
    for (int i = t; i < NBKT; i += 256)
        cur[i] = bbase[i] + block_off[blockIdx.x * NBKT + i];
    __syncthreads();
    int mi = flags[1];
    int base = blockIdx.x * EPB;
    for (int j = t; j < EPB; j += 256) {
        int e = base + j;
        if (e < N_EDGES) {
            int d = load_dst(ei, mi, e);
            int s = load_src(ei, mi, e);
            int p = atomicAdd(&cur[d >> BSHIFT], 1);
            bedges[p] = ((unsigned int)s << BSHIFT) | (unsigned int)(d & 511);
        }
    }
}

__global__ __launch_bounds__(512) void k_bucket_csr(const unsigned int* __restrict__ bedges,
                                                    const int* __restrict__ bbase,
                                                    int* __restrict__ rowptr,
                                                    float* __restrict__ dinv,
                                                    int* __restrict__ col) {
    __shared__ int cnt[512];
    __shared__ int cur[512];
    int b = blockIdx.x, t = threadIdx.x;
    int ebeg = bbase[b], eend = bbase[b + 1];
    cnt[t] = 0;
    __syncthreads();
    for (int j = ebeg + t; j < eend; j += 512)
        atomicAdd(&cnt[bedges[j] & 511], 1);
    __syncthreads();
    int v = cnt[t];
    cur[t] = v; __syncthreads();
    for (int off = 1; off < 512; off <<= 1) {
        int a = (t >= off) ? cur[t - off] : 0;
        __syncthreads();
        cur[t] += a;
        __syncthreads();
    }
    int excl = cur[t] - v;
    int node = b * 512 + t;
    if (node < N_NODES) {
        rowptr[node] = ebeg + excl;
        float dd = (float)v; if (dd < 1.f) dd = 1.f;
        dinv[node] = rsqrtf(dd);
    } else if (node == N_NODES) {
        rowptr[N_NODES] = ebeg + excl;  // == N_EDGES (no dst >= N_NODES exists)
    }
    __syncthreads();
    cur[t] = ebeg + excl;
    __syncthreads();
    for (int j = ebeg + t; j < eend; j += 512) {
        unsigned int pk = bedges[j];
        int p = atomicAdd(&cur[pk & 511], 1);
        col[p] = (int)(pk >> BSHIFT);
    }
}

// ============================================================================
// GEMM1: H1[N,128] = dinv[row] * (x[N,512] @ W0[128,512]^T)  (src-prescaled)
// async gload_lds, double-buffered, counted vmcnt(6) depth-2 pipeline.
// ============================================================================
#define G1_BUF 24576
#define G1_BOFF 16384

// ---- fp32-input fast path --------------------------------------------------
__device__ __forceinline__ void gemm1_f32_async(const float* __restrict__ xg,
                                                const unsigned short* __restrict__ w0n,
                                                const float* __restrict__ dinv,
                                                unsigned short* __restrict__ h1,
                                                char* __restrict__ smem,
                                                int node0, int t) {
    const int w = t >> 6;
    const int lane = t & 63;
    const int r16 = lane & 15;
    const int quad = lane >> 4;

    f32x4 acc[2][8];
#pragma unroll
    for (int m = 0; m < 2; m++)
#pragma unroll
        for (int c = 0; c < 8; c++) acc[m][c] = (f32x4){0.f, 0.f, 0.f, 0.f};

    const int lrow = lane >> 3;
    const int lch = (lane & 7) ^ lrow;
    const float* pa[4];
#pragma unroll
    for (int g = 0; g < 4; g++) {
        int r = node0 + w * 32 + 8 * g + lrow;
        if (r >= N_NODES) r = N_NODES - 1;
        pa[g] = xg + (size_t)r * IN_C + lch * 4;
    }
    const unsigned short* pb[2];
#pragma unroll
    for (int g = 0; g < 2; g++)
        pb[g] = w0n + (size_t)((2 * w + g) * 16 + r16) * IN_C + quad * 8;

    auto stage = [&](int buf, int ks) {
        char* Ab = smem + buf * G1_BUF + w * 4096;
        char* Bb = smem + buf * G1_BUF + G1_BOFF + w * 2048;
        glds16(pa[0] + ks, Ab);
        glds16(pa[1] + ks, Ab + 1024);
        glds16(pa[2] + ks, Ab + 2048);
        glds16(pa[3] + ks, Ab + 3072);
        glds16(pb[0] + ks, Bb);
        glds16(pb[1] + ks, Bb + 1024);
    };

    const int swz = r16 & 7;

    auto compute = [&](int buf) {
        const char* Ab = smem + buf * G1_BUF;
        const char* Bb = Ab + G1_BOFF;
        bf16x8 a[2];
#pragma unroll
        for (int m = 0; m < 2; m++) {
            int rowb = (w * 32 + m * 16 + r16) * 128;
            int c0 = ((2 * quad) ^ swz) * 16;
            int c1 = ((2 * quad + 1) ^ swz) * 16;
            float4 fa = *reinterpret_cast<const float4*>(Ab + rowb + c0);
            float4 fb = *reinterpret_cast<const float4*>(Ab + rowb + c1);
            a[m] = (bf16x8){(short)f2bf(fa.x), (short)f2bf(fa.y), (short)f2bf(fa.z), (short)f2bf(fa.w),
                            (short)f2bf(fb.x), (short)f2bf(fb.y), (short)f2bf(fb.z), (short)f2bf(fb.w)};
        }
#pragma unroll
        for (int ct = 0; ct < 8; ct++) {
            bf16x8 b = *reinterpret_cast<const bf16x8*>(Bb + ct * 1024 + lane * 16);
            acc[0][ct] = __builtin_amdgcn_mfma_f32_16x16x32_bf16(a[0], b, acc[0][ct], 0, 0, 0);
            acc[1][ct] = __builtin_amdgcn_mfma_f32_16x16x32_bf16(a[1], b, acc[1][ct], 0, 0, 0);
        }
    };

    stage(0, 0);
    stage(1, 32);
    for (int tt = 0; tt < 14; ++tt) {
        asm volatile("s_waitcnt vmcnt(6)" ::: "memory");
        __builtin_amdgcn_sched_barrier(0);
        __builtin_amdgcn_s_barrier();
        compute(tt & 1);
        __builtin_amdgcn_s_barrier();
        stage(tt & 1, (tt + 2) * 32);
    }
    asm volatile("s_waitcnt vmcnt(6)" ::: "memory");
    __builtin_amdgcn_sched_barrier(0);
    __builtin_amdgcn_s_barrier();
    compute(0);
    asm volatile("s_waitcnt vmcnt(0)" ::: "memory");
    __builtin_amdgcn_sched_barrier(0);
    __builtin_amdgcn_s_barrier();
    compute(1);

#pragma unroll
    for (int m = 0; m < 2; m++) {
#pragma unroll
        for (int r = 0; r < 4; r++) {
            int row = node0 + w * 32 + m * 16 + quad * 4 + r;
            if (row < N_NODES) {
                float dv = dinv[row];
#pragma unroll
                for (int ct = 0; ct < 8; ct++)
                    h1[(size_t)row * HID_C + ct * 16 + r16] = f2bf(acc[m][ct][r] * dv);
            }
        }
    }
}

// ---- bf16-input path (same layout, conservative drain0 loop) ---------------
__device__ __forceinline__ void gemm1_bf16_async(const unsigned short* __restrict__ xg,
                                                 const unsigned short* __restrict__ w0n,
                                                 const float* __restrict__ dinv,
                                                 unsigned short* __restrict__ h1,
                                                 unsigned short* __restrict__ smem,
                                                 int node0, int t) {
    const int w = t >> 6;
    const int lane = t & 63;
    const int r16 = lane & 15;
    const int quad = lane >> 4;

    f32x4 acc[2][8];
#pragma unroll
    for (int m = 0; m < 2; m++)
#pragma unroll
        for (int c = 0; c < 8; c++) acc[m][c] = (f32x4){0.f, 0.f, 0.f, 0.f};

    int rA0 = node0 + (2 * w) * 16 + r16;     if (rA0 >= N_NODES) rA0 = N_NODES - 1;
    int rA1 = node0 + (2 * w + 1) * 16 + r16; if (rA1 >= N_NODES) rA1 = N_NODES - 1;
    const unsigned short* pa0 = xg + (size_t)rA0 * IN_C + quad * 8;
    const unsigned short* pa1 = xg + (size_t)rA1 * IN_C + quad * 8;
    const unsigned short* pb0 = w0n + (size_t)((2 * w) * 16 + r16) * IN_C + quad * 8;
    const unsigned short* pb1 = w0n + (size_t)((2 * w + 1) * 16 + r16) * IN_C + quad * 8;

    auto stage = [&](int buf, int ks) {
        unsigned short* a = smem + buf * 8192 + (2 * w) * 512;
        glds16(pa0 + ks, a);
        glds16(pa1 + ks, a + 512);
        glds16(pb0 + ks, a + 4096);
        glds16(pb1 + ks, a + 4096 + 512);
    };

    const int fo = quad * 128 + r16 * 8;

    auto compute = [&](int buf) {
        const unsigned short* Ab = smem + buf * 8192;
        const unsigned short* Bb = Ab + 4096;
        bf16x8 a0 = *reinterpret_cast<const bf16x8*>(Ab + (2 * w) * 512 + fo);
        bf16x8 a1 = *reinterpret_cast<const bf16x8*>(Ab + (2 * w + 1) * 512 + fo);
#pragma unroll
        for (int ct = 0; ct < 8; ct++) {
            bf16x8 b = *reinterpret_cast<const bf16x8*>(Bb + ct * 512 + fo);
            acc[0][ct] = __builtin_amdgcn_mfma_f32_16x16x32_bf16(a0, b, acc[0][ct], 0, 0, 0);
            acc[1][ct] = __builtin_amdgcn_mfma_f32_16x16x32_bf16(a1, b, acc[1][ct], 0, 0, 0);
        }
    };

    stage(0, 0);
    __syncthreads();
    for (int tt = 0; tt < 15; ++tt) {
        int cur = tt & 1;
        stage(cur ^ 1, (tt + 1) * 32);
        compute(cur);
        __syncthreads();
    }
    compute(1);

#pragma unroll
    for (int m = 0; m < 2; m++) {
#pragma unroll
        for (int r = 0; r < 4; r++) {
            int row = node0 + w * 32 + m * 16 + quad * 4 + r;
            if (row < N_NODES) {
                float dv = dinv[row];
#pragma unroll
                for (int ct = 0; ct < 8; ct++)
                    h1[(size_t)row * HID_C + ct * 16 + r16] = f2bf(acc[m][ct][r] * dv);
            }
        }
    }
}

__global__ __launch_bounds__(256, 3) void k_gemm1(const void* __restrict__ x,
                                                  const unsigned short* __restrict__ w0n,
                                                  const int* __restrict__ flags,
                                                  const float* __restrict__ dinv,
                                                  unsigned short* __restrict__ h1) {
    __shared__ __align__(16) char smem[2 * G1_BUF];  // 49152 B -> 3 blocks/CU
    int node0 = blockIdx.x * 128;
    int t = threadIdx.x;
    if (flags[0]) gemm1_bf16_async((const unsigned short*)x, w0n, dinv, h1,
                                   (unsigned short*)smem, node0, t);
    else          gemm1_f32_async((const float*)x, w0n, dinv, h1, smem, node0, t);
}

// ---- Fused Agg1 (+bias+relu) + GEMM2 (MFMA) --------------------------------
// Block = 4 waves, 16 nodes (4 sequential per wave). Gather path identical to
// the verified scalarized agg1; packed bf16 row goes to LDS H[16][68] (uint,
// +4 pad -> 16B-aligned b128 rows, 2-way-max bank alias). One barrier, then
// wave 0 runs the verified gemm2 MFMA fragment with A from LDS:
// p2[16 rows] = dinv * (H @ W1p^T). h2 never touches HBM.
__global__ __launch_bounds__(256) void k_agg1g2(const int* __restrict__ rowptr,
                                                const int* __restrict__ col,
                                                const float* __restrict__ dinv,
                                                const unsigned int* __restrict__ h1v,
                                                const float* __restrict__ b0n,
                                                const unsigned short* __restrict__ w1p,
                                                float* __restrict__ p2) {
    __shared__ unsigned int H[16][68];
    int w = threadIdx.x >> 6;
    int lane = threadIdx.x & 63;
    int nb = blockIdx.x * 16;   // N_NODES = 6250 * 16 exactly
    float bl = b0n[2 * lane], bh = b0n[2 * lane + 1];
#pragma unroll
    for (int i = 0; i < 4; i++) {
        int d = nb + w * 4 + i;
        int beg = __builtin_amdgcn_readfirstlane(rowptr[d]);
        int end = __builtin_amdgcn_readfirstlane(rowptr[d + 1]);
        float a0 = 0.f, a1 = 0.f;
        for (int j0 = beg; j0 < end; j0 += 16) {
            int s[16];
            float m[16];
#pragma unroll
            for (int q = 0; q < 16; q++) {
                int jj = j0 + q;
                int jc = jj < end ? jj : end - 1;  // uniform -> SALU cselect
                s[q] = col[jc];                    // uniform addr -> s_load
                m[q] = jj < end ? 1.f : 0.f;
            }
            unsigned int r[16];
#pragma unroll
            for (int q = 0; q < 16; q++) {
                const unsigned int* rp = h1v + (size_t)s[q] * 64;  // uniform base
                r[q] = rp[lane];
            }
#pragma unroll
            for (int q = 0; q < 16; q++) {
                a0 += m[q] * bf2f_lo(r[q]);
                a1 += m[q] * bf2f_hi(r[q]);
            }
        }
        float dv = dinv[d];
        float o0 = a0 * dv + bl;
        float o1 = a1 * dv + bh;
        o0 = o0 > 0.f ? o0 : 0.f;
        o1 = o1 > 0.f ? o1 : 0.f;
        H[w * 4 + i][lane] = (unsigned int)f2bf(o0) | ((unsigned int)f2bf(o1) << 16);
    }
    __syncthreads();
    if (w != 0) return;

    int r16 = lane & 15;
    int quad = lane >> 4;
    f32x4 acc[3];
#pragma unroll
    for (int c = 0; c < 3; c++) acc[c] = (f32x4){0.f, 0.f, 0.f, 0.f};

    const unsigned short* brow = w1p + (size_t)r16 * HID_C + quad * 8;
#pragma unroll
    for (int k0 = 0; k0 < HID_C; k0 += 32) {
        bf16x8 a = *reinterpret_cast<const bf16x8*>(&H[r16][k0 / 2 + quad * 4]);
#pragma unroll
        for (int ct = 0; ct < 3; ct++) {
            bf16x8 b = *reinterpret_cast<const bf16x8*>(brow + (size_t)ct * 16 * HID_C + k0);
            acc[ct] = __builtin_amdgcn_mfma_f32_16x16x32_bf16(a, b, acc[ct], 0, 0, 0);
        }
    }

    float dvv[4];
#pragma unroll
    for (int r = 0; r < 4; r++) dvv[r] = dinv[nb + quad * 4 + r];

#pragma unroll
    for (int ct = 0; ct < 3; ct++) {
        int chan = ct * 16 + r16;
        if (chan < OUT_C) {
#pragma unroll
            for (int r = 0; r < 4; r++) {
                p2[(size_t)(nb + quad * 4 + r) * OUT_C + chan] = acc[ct][r] * dvv[r];
            }
        }
    }
}

// ---- Agg layer 2 (+bias): scalarized col path, masked 16-wide --------------
__global__ __launch_bounds__(256) void k_agg2(const int* __restrict__ rowptr,
                                              const int* __restrict__ col,
                                              const float* __restrict__ dinv,
                                              const float* __restrict__ p2,
                                              const float* __restrict__ b1n,
                                              const int* __restrict__ flags,
                                              void* __restrict__ out) {
    int w = threadIdx.x >> 6;
    int lane = threadIdx.x & 63;
    int d = blockIdx.x * 4 + w;
    if (d >= N_NODES || lane >= OUT_C) return;
    int beg = __builtin_amdgcn_readfirstlane(rowptr[d]);
    int end = __builtin_amdgcn_readfirstlane(rowptr[d + 1]);
    float acc = 0.f;
    for (int j0 = beg; j0 < end; j0 += 16) {
        int s[16];
        float m[16];
#pragma unroll
        for (int q = 0; q < 16; q++) {
            int jj = j0 + q;
            int jc = jj < end ? jj : end - 1;
            s[q] = col[jc];                    // uniform -> s_load
            m[q] = jj < end ? 1.f : 0.f;
        }
        float r[16];
#pragma unroll
        for (int q = 0; q < 16; q++) {
            const float* rp = p2 + (size_t)s[q] * OUT_C;       // uniform base
            r[q] = rp[lane];
        }
#pragma unroll
        for (int q = 0; q < 16; q++) acc += m[q] * r[q];
    }
    float v = acc * dinv[d] + b1n[lane];
    size_t idx = (size_t)d * OUT_C + lane;
    if (flags[0]) ((unsigned short*)out)[idx] = f2bf(v);
    else          ((float*)out)[idx] = v;
}

extern "C" void kernel_launch(void* const* d_in, const int* in_sizes, int n_in,
                              void* d_out, int out_size, void* d_ws, size_t ws_size,
                              hipStream_t stream) {
    const void* x  = d_in[0];
    const int* ei  = (const int*)d_in[1];
    const void* W0 = d_in[2];
    const void* b0 = d_in[3];
    const void* W1 = d_in[4];
    const void* b1 = d_in[5];

    char* ws = (char*)d_ws;
    size_t off = 0;
    auto alloc = [&](size_t bytes) {
        char* p = ws + off;
        off += (bytes + 511) & ~(size_t)511;
        return p;
    };
    // Total footprint ~56 MB.
    int*   flags   = (int*)  alloc(sizeof(int) * 2);
    int*   rowptr  = (int*)  alloc(sizeof(int) * (N_NODES + 1));
    float* dinv    = (float*)alloc(sizeof(float) * N_NODES);
    int*   col     = (int*)  alloc(sizeof(int) * N_EDGES);
    int*   bcnt    = (int*)  alloc(sizeof(int) * NBKT);
    int*   bbase   = (int*)  alloc(sizeof(int) * (NBKT + 1));
    int*   bloff   = (int*)  alloc(sizeof(int) * NPART * NBKT);
    unsigned int* bedges = (unsigned int*)alloc(sizeof(unsigned int) * N_EDGES);
    unsigned short* w0n = (unsigned short*)alloc(sizeof(unsigned short) * IN_C * HID_C);
    unsigned short* w1n = (unsigned short*)alloc(sizeof(unsigned short) * OUT_CP * HID_C);
    float* b0n = (float*)alloc(sizeof(float) * HID_C);
    float* b1n = (float*)alloc(sizeof(float) * OUT_C);
    unsigned short* h1 = (unsigned short*)alloc(sizeof(unsigned short) * (size_t)N_NODES * HID_C);
    float* p2 = (float*)alloc(sizeof(float) * (size_t)N_NODES * OUT_C);  // no alias: h1 live in k_agg1g2

    k_detect<<<1, 64, 0, stream>>>((const unsigned int*)x, ei, flags);
    hipMemsetAsync(w1n, 0, sizeof(unsigned short) * OUT_CP * HID_C, stream);
    k_norm_w<<<(NW_TOTAL + 255) / 256, 256, 0, stream>>>(W0, W1, b0, b1, flags, w0n, w1n, b0n, b1n);

    hipMemsetAsync(bcnt, 0, sizeof(int) * NBKT, stream);
    k_part1<<<NPART, 256, 0, stream>>>(ei, flags, bcnt, bloff);
    k_scan_bkt<<<1, 256, 0, stream>>>(bcnt, bbase);
    k_part2<<<NPART, 256, 0, stream>>>(ei, flags, bbase, bloff, bedges);
    k_bucket_csr<<<NBKT, 512, 0, stream>>>(bedges, bbase, rowptr, dinv, col);

    k_gemm1<<<(N_NODES + 127) / 128, 256, 0, stream>>>(x, w0n, flags, dinv, h1);
    k_agg1g2<<<N_NODES / 16, 256, 0, stream>>>(rowptr, col, dinv,
                                               (const unsigned int*)h1, b0n,
                                               w1n, p2);
    k_agg2<<<(N_NODES + 3) / 4, 256, 0, stream>>>(rowptr, col, dinv, p2, b1n, flags, d_out);
}